// Round 2
// baseline (32.587 us; speedup 1.0000x reference)
//
#include <hip/hip_runtime.h>

// Lennard-Jones N-body forces, N=4096, D=3.
// out = [dq (N*3), dp (N*3)], dq = p/m, dp[i] = sum_j 96*(2*sr6^2 - sr6)/d2 * disp.
// (sqrt-free form: -dVdr/r = 24*EPS*(2*sr12 - sr6)/r^2, EPS=4, SIGMA=1)
//
// NaN-proofing: fp32 fast path only when d2 >= 0.01 (coef provably finite);
// close pairs take an fp64 path into separate f64 accumulators; partials are
// f64 in d_ws; single f64->f32 cast at the end. Diagonal uses the reference's
// own trick (d2 -> 1, disp = 0 -> contribution exactly 0).

#define FB_T 0.01f  // d2 below this -> fp64 fallback path (r < 0.1)

__global__ void lj_partial_kernel(const float* __restrict__ q,
                                  double* __restrict__ part,
                                  int n, int chunk) {
    extern __shared__ float qs[];  // chunk*3 floats
    const int i  = blockIdx.x * blockDim.x + threadIdx.x;
    const int j0 = blockIdx.y * chunk;

    for (int t = threadIdx.x; t < chunk * 3; t += blockDim.x)
        qs[t] = q[j0 * 3 + t];
    __syncthreads();

    const float qx = q[3 * i + 0];
    const float qy = q[3 * i + 1];
    const float qz = q[3 * i + 2];

    float  fx = 0.0f, fy = 0.0f, fz = 0.0f;   // fast-path accumulator
    double gx = 0.0,  gy = 0.0,  gz = 0.0;    // close-pair (f64) accumulator

    for (int jj = 0; jj < chunk; ++jj) {
        const float dx = qx - qs[3 * jj + 0];
        const float dy = qy - qs[3 * jj + 1];
        const float dz = qz - qs[3 * jj + 2];
        float d2 = __fmaf_rn(dx, dx, __fmaf_rn(dy, dy, dz * dz));
        if (j0 + jj == i) d2 = 1.0f;  // diagonal: disp==0 zeroes contribution

        if (d2 >= FB_T) {
            // fp32 fast path: coef = 96*(2*sr6^2 - sr6)/d2, all finite
            const float inv = __builtin_amdgcn_rcpf(d2);
            const float s6  = inv * inv * inv;
            const float t   = __fmaf_rn(s6 + s6, s6, -s6);  // 2*s6^2 - s6
            const float c   = 96.0f * t * inv;
            fx = __fmaf_rn(c, dx, fx);
            fy = __fmaf_rn(c, dy, fy);
            fz = __fmaf_rn(c, dz, fz);
        } else {
            // rare close pair: full fp64, finite by construction
            const double ddx = (double)dx, ddy = (double)dy, ddz = (double)dz;
            const double d2d = ddx * ddx + ddy * ddy + ddz * ddz;
            if (d2d > 0.0) {  // exact-duplicate guard
                const double inv = 1.0 / d2d;
                const double s6  = inv * inv * inv;
                const double c   = 96.0 * (2.0 * s6 * s6 - s6) * inv;
                gx += c * ddx;
                gy += c * ddy;
                gz += c * ddz;
            }
        }
    }

    double* dst = part + (size_t)blockIdx.y * (size_t)n * 3;
    dst[3 * i + 0] = (double)fx + gx;
    dst[3 * i + 1] = (double)fy + gy;
    dst[3 * i + 2] = (double)fz + gz;
}

__global__ void lj_finalize_kernel(const float* __restrict__ p,
                                   const float* __restrict__ m,
                                   const double* __restrict__ part,
                                   float* __restrict__ out,
                                   int n, int jsplit) {
    const int idx = blockIdx.x * blockDim.x + threadIdx.x;
    if (idx >= n * 3) return;
    // dq = p / m (exact rounding; this output has a finite threshold)
    out[idx] = __fdiv_rn(p[idx], m[idx / 3]);
    // dp = fixed-order f64 sum of partials -> deterministic, NaN-free
    double acc = 0.0;
    for (int k = 0; k < jsplit; ++k)
        acc += part[(size_t)k * (size_t)n * 3 + idx];
    out[n * 3 + idx] = (float)acc;
}

extern "C" void kernel_launch(void* const* d_in, const int* in_sizes, int n_in,
                              void* d_out, int out_size, void* d_ws, size_t ws_size,
                              hipStream_t stream) {
    const float* q = (const float*)d_in[0];
    const float* p = (const float*)d_in[1];
    const float* m = (const float*)d_in[2];
    // d_in[3] is t (unused by the math)

    const int n = in_sizes[0] / 3;  // 4096
    float*  out  = (float*)d_out;
    double* part = (double*)d_ws;

    // largest power-of-2 j-split whose f64 partial buffer fits the workspace
    int jsplit = 64;
    while (jsplit > 1 &&
           (size_t)jsplit * (size_t)n * 3 * sizeof(double) > ws_size)
        jsplit >>= 1;

    const int chunk = n / jsplit;
    const int BI = 256;

    dim3 grid(n / BI, jsplit);
    lj_partial_kernel<<<grid, BI, chunk * 3 * sizeof(float), stream>>>(q, part, n, chunk);

    const int nb = (n * 3 + 255) / 256;
    lj_finalize_kernel<<<nb, 256, 0, stream>>>(p, m, part, out, n, jsplit);
}